// Round 1
// baseline (887.722 us; speedup 1.0000x reference)
//
#include <hip/hip_runtime.h>
#include <math.h>

// GraphBlock: 2x GATConv(H=2 heads, C=64, concat=False) + BN(train) + GELU + skip + mean-pool
// N=50000, E=1.6M, F_IN=C=64, B=64

__device__ __forceinline__ float lrelu(float x){ return x > 0.f ? x : 0.2f*x; }
__device__ __forceinline__ float gelu_tanh(float x){
  const float k0 = 0.7978845608028654f; // sqrt(2/pi)
  const float k1 = 0.044715f;
  float t = tanhf(k0 * fmaf(k1*x*x, x, x));
  return 0.5f*x*(1.f + t);
}

// ---- CSR build ----
__global__ void k_count(const int* __restrict__ dst, int* __restrict__ deg, int E){
  int i = blockIdx.x*blockDim.x + threadIdx.x;
  if (i < E) atomicAdd(&deg[dst[i]], 1);
}

__global__ void k_scan1(const int* __restrict__ deg, int* __restrict__ bsum, int N){
  int t = threadIdx.x;
  int base = blockIdx.x*1024 + t*4;
  int s = 0;
  #pragma unroll
  for (int i=0;i<4;i++){ int idx=base+i; if (idx<N) s += deg[idx]; }
  __shared__ int ls[256];
  ls[t]=s; __syncthreads();
  for (int o=128;o>0;o>>=1){ if (t<o) ls[t]+=ls[t+o]; __syncthreads(); }
  if (t==0) bsum[blockIdx.x]=ls[0];
}

__global__ void k_scan2(int* __restrict__ bsum, int nb, int* __restrict__ ptr, int N, int E){
  int l = threadIdx.x;
  int v = (l<nb)? bsum[l] : 0;
  int x = v;
  #pragma unroll
  for (int o=1;o<64;o<<=1){ int y = __shfl_up(x,o); if (l>=o) x += y; }
  if (l<nb) bsum[l] = x - v;   // exclusive
  if (l==0) ptr[N] = E;
}

__global__ void k_scan3(const int* __restrict__ deg, const int* __restrict__ bsum,
                        int* __restrict__ ptr, int* __restrict__ cur, int N){
  int t = threadIdx.x;
  int base = blockIdx.x*1024 + t*4;
  int v[4]; int s=0;
  #pragma unroll
  for (int i=0;i<4;i++){ int idx=base+i; v[i] = (idx<N)? deg[idx] : 0; s += v[i]; }
  __shared__ int ls[256];
  ls[t]=s; __syncthreads();
  for (int o=1;o<256;o<<=1){
    int y = (t>=o)? ls[t-o] : 0;
    __syncthreads();
    ls[t] += y;
    __syncthreads();
  }
  int p = ls[t] - s + bsum[blockIdx.x];
  #pragma unroll
  for (int i=0;i<4;i++){
    int idx=base+i;
    if (idx<N){ ptr[idx]=p; cur[idx]=p; }
    p += v[i];
  }
}

__global__ void k_fill(const int* __restrict__ src, const int* __restrict__ dst,
                       int* __restrict__ cur, int* __restrict__ srcs, int E){
  int i = blockIdx.x*blockDim.x + threadIdx.x;
  if (i < E){
    int pos = atomicAdd(&cur[dst[i]], 1);
    srcs[pos] = src[i];
  }
}

// ---- GEMM [N,64]@[64,128] + attention dots; one wave per row ----
__global__ void k_gemm_att(const float* __restrict__ X, const float* __restrict__ W,
                           const float* __restrict__ att_s, const float* __restrict__ att_d,
                           float* __restrict__ Hout, float* __restrict__ a_s,
                           float* __restrict__ a_d, int N){
  __shared__ float2 Wl[64*64];
  int t = threadIdx.x;
  const float2* W2p = (const float2*)W;
  #pragma unroll
  for (int i=0;i<16;i++) Wl[t + 256*i] = W2p[t + 256*i];
  __syncthreads();
  int wave = t>>6, lane = t&63;
  float as0 = att_s[2*lane], as1 = att_s[2*lane+1];
  float ad0 = att_d[2*lane], ad1 = att_d[2*lane+1];
  int r0 = blockIdx.x*16;
  for (int i=0;i<4;i++){
    int r = r0 + 4*i + wave;
    float xk = 0.f;
    if (r < N) xk = X[(size_t)r*64 + lane];
    float acc0=0.f, acc1=0.f;
    #pragma unroll
    for (int k=0;k<64;k++){
      float xv = __shfl(xk, k);
      float2 w = Wl[k*64 + lane];
      acc0 = fmaf(xv, w.x, acc0);
      acc1 = fmaf(xv, w.y, acc1);
    }
    if (r < N){
      float2 o; o.x = acc0; o.y = acc1;
      ((float2*)Hout)[(size_t)r*64 + lane] = o;
      float ps = acc0*as0 + acc1*as1;
      float pd = acc0*ad0 + acc1*ad1;
      #pragma unroll
      for (int o2=16;o2>0;o2>>=1){ ps += __shfl_xor(ps,o2); pd += __shfl_xor(pd,o2); }
      if (lane==0){ a_s[2*r]=ps; a_d[2*r]=pd; }
      else if (lane==32){ a_s[2*r+1]=ps; a_d[2*r+1]=pd; }
    }
  }
}

// ---- skip GEMM [N,64]@[64,64]; one wave per row ----
__global__ void k_skip(const float* __restrict__ X, const float* __restrict__ W,
                       float* __restrict__ out, int N){
  __shared__ float Wl[64*64];
  int t = threadIdx.x;
  #pragma unroll
  for (int i=0;i<16;i++) Wl[t + 256*i] = W[t + 256*i];
  __syncthreads();
  int wave = t>>6, lane = t&63;
  int r0 = blockIdx.x*16;
  for (int i=0;i<4;i++){
    int r = r0 + 4*i + wave;
    float xk = (r<N)? X[(size_t)r*64 + lane] : 0.f;
    float acc = 0.f;
    #pragma unroll
    for (int k=0;k<64;k++) acc = fmaf(__shfl(xk,k), Wl[k*64 + lane], acc);
    if (r<N) out[(size_t)r*64 + lane] = acc;
  }
}

// ---- GAT aggregation: one wave per node; self-loop implicit ----
__global__ void k_agg(const float* __restrict__ Hbig, const float* __restrict__ a_s,
                      const float* __restrict__ a_d, const int* __restrict__ ptr,
                      const int* __restrict__ srcs, const float* __restrict__ bias,
                      float* __restrict__ out, int N){
  int wid = (blockIdx.x*blockDim.x + threadIdx.x) >> 6;
  int lane = threadIdx.x & 63;
  if (wid >= N) return;
  int n = wid;
  float ad0 = a_d[2*n], ad1 = a_d[2*n+1];
  float sn0 = a_s[2*n], sn1 = a_s[2*n+1];
  int e0 = ptr[n], e1 = ptr[n+1];
  float sl0 = lrelu(sn0+ad0), sl1 = lrelu(sn1+ad1);
  // phase A: segment max (lanes parallel over edges) incl. self-loop
  float m0 = sl0, m1 = sl1;
  for (int i = e0 + lane; i < e1; i += 64){
    int s = srcs[i];
    m0 = fmaxf(m0, lrelu(a_s[2*s]   + ad0));
    m1 = fmaxf(m1, lrelu(a_s[2*s+1] + ad1));
  }
  #pragma unroll
  for (int o=32;o>0;o>>=1){ m0 = fmaxf(m0,__shfl_xor(m0,o)); m1 = fmaxf(m1,__shfl_xor(m1,o)); }
  // phase B: denom + message accumulation (serial wave-uniform edges)
  float w0 = expf(sl0 - m0), w1 = expf(sl1 - m1);
  float d0 = w0, d1 = w1;
  float2 hv = ((const float2*)Hbig)[(size_t)n*64 + lane];
  float ws = (lane < 32) ? w0 : w1;
  float acc0 = hv.x * ws, acc1 = hv.y * ws;
  for (int i = e0; i < e1; i++){
    int s = srcs[i];
    float e_0 = expf(lrelu(a_s[2*s]   + ad0) - m0);
    float e_1 = expf(lrelu(a_s[2*s+1] + ad1) - m1);
    d0 += e_0; d1 += e_1;
    float2 h2 = ((const float2*)Hbig)[(size_t)s*64 + lane];
    float wss = (lane < 32) ? e_0 : e_1;
    acc0 = fmaf(h2.x, wss, acc0);
    acc1 = fmaf(h2.y, wss, acc1);
  }
  float dsel = (lane < 32) ? d0 : d1;
  acc0 /= dsel; acc1 /= dsel;
  // head mean: lane l (<32) pairs with lane l+32 (head 1, same channels)
  float o0 = 0.5f*(acc0 + __shfl_xor(acc0, 32));
  float o1 = 0.5f*(acc1 + __shfl_xor(acc1, 32));
  if (lane < 32){
    float2 res; res.x = o0 + bias[2*lane]; res.y = o1 + bias[2*lane+1];
    ((float2*)out)[(size_t)n*32 + lane] = res;
  }
}

// ---- BN stats: per-channel sum / sumsq ----
__global__ void k_bnstats(const float* __restrict__ X, float* __restrict__ part, int N){
  int t = threadIdx.x; int c = t & 63; int sub = t >> 6;
  float s = 0.f, s2 = 0.f;
  for (int r = blockIdx.x*4 + sub; r < N; r += gridDim.x*4){
    float v = X[(size_t)r*64 + c];
    s += v; s2 = fmaf(v, v, s2);
  }
  __shared__ float ls[256], lq[256];
  ls[t] = s; lq[t] = s2; __syncthreads();
  if (t < 64){
    s  = ls[t] + ls[t+64] + ls[t+128] + ls[t+192];
    s2 = lq[t] + lq[t+64] + lq[t+128] + lq[t+192];
    atomicAdd(&part[t], s);
    atomicAdd(&part[64+t], s2);
  }
}

__global__ void k_bnfinal(const float* __restrict__ part, const float* __restrict__ gamma,
                          const float* __restrict__ beta, float* __restrict__ bnb, int N){
  int c = threadIdx.x;
  float mu  = part[c] / (float)N;
  float var = part[64+c] / (float)N - mu*mu;
  var = fmaxf(var, 0.f);
  float sc = gamma[c] * rsqrtf(var + 1e-5f);
  bnb[c] = sc;
  bnb[64+c] = beta[c] - mu*sc;
}

// ---- hmid = gelu(bn(g1) + skip + skipb) ----
__global__ void k_fuse1(const float* __restrict__ g1, const float* __restrict__ bn,
                        const float* __restrict__ skip, const float* __restrict__ skipb,
                        float* __restrict__ hmid, int total){
  int i = blockIdx.x*blockDim.x + threadIdx.x;
  if (i < total){
    int c = i & 63;
    float v = fmaf(g1[i], bn[c], bn[64+c]) + skip[i] + skipb[c];
    hmid[i] = gelu_tanh(v);
  }
}

// ---- final: gelu(bn(g2)+hmid), pooled sums per batch (batch_index sorted) ----
__global__ void k_fusepool(const float* __restrict__ g2, const float* __restrict__ bn,
                           const float* __restrict__ hmid, const int* __restrict__ batch,
                           float* __restrict__ pool, float* __restrict__ cnt, int N){
  int t = threadIdx.x; int c = t & 63; int sub = t >> 6;
  int r0 = blockIdx.x*64;
  float scale = bn[c], shift = bn[64+c];
  float acc = 0.f, ca = 0.f; int curb = -1;
  for (int r = r0 + sub; r < N && r < r0 + 64; r += 4){
    int b = batch[r];
    if (b != curb){
      if (curb >= 0){
        atomicAdd(&pool[curb*64 + c], acc);
        if (c == 0) atomicAdd(&cnt[curb], ca);
      }
      acc = 0.f; ca = 0.f; curb = b;
    }
    float v = gelu_tanh(fmaf(g2[(size_t)r*64 + c], scale, shift) + hmid[(size_t)r*64 + c]);
    acc += v; ca += 1.f;
  }
  if (curb >= 0){
    atomicAdd(&pool[curb*64 + c], acc);
    if (c == 0) atomicAdd(&cnt[curb], ca);
  }
}

__global__ void k_out(const float* __restrict__ pool, const float* __restrict__ cnt,
                      float* __restrict__ out, int M){
  int i = blockIdx.x*blockDim.x + threadIdx.x;
  if (i < M) out[i] = pool[i] / fmaxf(cnt[i>>6], 1.f);
}

extern "C" void kernel_launch(void* const* d_in, const int* in_sizes, int n_in,
                              void* d_out, int out_size, void* d_ws, size_t ws_size,
                              hipStream_t stream) {
  const float* x     = (const float*)d_in[0];
  const int*   ei    = (const int*)  d_in[1];
  const int*   batch = (const int*)  d_in[2];
  const float* W1    = (const float*)d_in[3];
  const float* as1   = (const float*)d_in[4];
  const float* ad1   = (const float*)d_in[5];
  const float* b1    = (const float*)d_in[6];
  const float* skW   = (const float*)d_in[7];
  const float* skb   = (const float*)d_in[8];
  const float* gm1   = (const float*)d_in[9];
  const float* bt1   = (const float*)d_in[10];
  const float* W2    = (const float*)d_in[11];
  const float* as2   = (const float*)d_in[12];
  const float* ad2   = (const float*)d_in[13];
  const float* b2    = (const float*)d_in[14];
  const float* gm2   = (const float*)d_in[15];
  const float* bt2   = (const float*)d_in[16];

  int N = in_sizes[2];
  int E = in_sizes[1] / 2;
  const int* esrc = ei;
  const int* edst = ei + E;

  char* wp = (char*)d_ws;
  size_t off = 0;
  auto alloc = [&](size_t bytes)->void*{
    off = (off + 255) & ~(size_t)255;
    void* p = wp + off;
    off += bytes;
    return p;
  };
  int*   deg  = (int*)  alloc((size_t)N*4);
  int*   ptr  = (int*)  alloc((size_t)(N+1)*4);
  int*   cur  = (int*)  alloc((size_t)N*4);
  int*   bsum = (int*)  alloc(64*4);
  int*   srcs = (int*)  alloc((size_t)E*4);
  float* hbig = (float*)alloc((size_t)N*128*4);
  float* a_s  = (float*)alloc((size_t)N*2*4);
  float* a_d  = (float*)alloc((size_t)N*2*4);
  float* gout = (float*)alloc((size_t)N*64*4);   // GAT raw output (both layers)
  float* skv  = (float*)alloc((size_t)N*64*4);   // x @ skipW
  float* hmid = (float*)alloc((size_t)N*64*4);   // layer-1 final output
  float* zz   = (float*)alloc((size_t)(128+128+4096+64)*4); // zero zone
  float* part1 = zz;
  float* part2 = zz + 128;
  float* pool  = zz + 256;
  float* cnt   = zz + 256 + 4096;
  float* bnb1 = (float*)alloc(128*4);
  float* bnb2 = (float*)alloc(128*4);

  hipMemsetAsync(deg, 0, (size_t)N*4, stream);
  hipMemsetAsync(zz, 0, (size_t)(128+128+4096+64)*4, stream);

  const int TB = 256;
  int egrid = (E + TB - 1) / TB;
  int nch = (N + 1023) / 1024;
  int gb = (N + 15) / 16;

  // CSR build
  k_count<<<egrid, TB, 0, stream>>>(edst, deg, E);
  k_scan1<<<nch, 256, 0, stream>>>(deg, bsum, N);
  k_scan2<<<1, 64, 0, stream>>>(bsum, nch, ptr, N, E);
  k_scan3<<<nch, 256, 0, stream>>>(deg, bsum, ptr, cur, N);
  k_fill<<<egrid, TB, 0, stream>>>(esrc, edst, cur, srcs, E);

  // layer 1
  k_gemm_att<<<gb, 256, 0, stream>>>(x, W1, as1, ad1, hbig, a_s, a_d, N);
  k_skip<<<gb, 256, 0, stream>>>(x, skW, skv, N);
  k_agg<<<(N+3)/4, 256, 0, stream>>>(hbig, a_s, a_d, ptr, srcs, b1, gout, N);
  k_bnstats<<<256, 256, 0, stream>>>(gout, part1, N);
  k_bnfinal<<<1, 64, 0, stream>>>(part1, gm1, bt1, bnb1, N);
  k_fuse1<<<(N*64 + 255)/256, 256, 0, stream>>>(gout, bnb1, skv, skb, hmid, N*64);

  // layer 2
  k_gemm_att<<<gb, 256, 0, stream>>>(hmid, W2, as2, ad2, hbig, a_s, a_d, N);
  k_agg<<<(N+3)/4, 256, 0, stream>>>(hbig, a_s, a_d, ptr, srcs, b2, gout, N);
  k_bnstats<<<256, 256, 0, stream>>>(gout, part2, N);
  k_bnfinal<<<1, 64, 0, stream>>>(part2, gm2, bt2, bnb2, N);

  // fuse + pool
  k_fusepool<<<(N+63)/64, 256, 0, stream>>>(gout, bnb2, hmid, batch, pool, cnt, N);
  k_out<<<(out_size + 255)/256, 256, 0, stream>>>(pool, cnt, (float*)d_out, out_size);
}

// Round 2
// 618.883 us; speedup vs baseline: 1.4344x; 1.4344x over previous
//
#include <hip/hip_runtime.h>
#include <math.h>

// GraphBlock: 2x GATConv(H=2 heads, C=64, concat=False) + BN(train) + GELU + skip + mean-pool
// N=50000, E=1.6M, F_IN=C=64, B=64

__device__ __forceinline__ float lrelu(float x){ return x > 0.f ? x : 0.2f*x; }
__device__ __forceinline__ float gelu_tanh(float x){
  const float k0 = 0.7978845608028654f; // sqrt(2/pi)
  const float k1 = 0.044715f;
  float t = tanhf(k0 * fmaf(k1*x*x, x, x));
  return 0.5f*x*(1.f + t);
}

// ---- CSR build ----
__global__ void k_count(const int* __restrict__ dst, int* __restrict__ deg, int E){
  int i = blockIdx.x*blockDim.x + threadIdx.x;
  if (i < E) atomicAdd(&deg[dst[i]], 1);
}

__global__ void k_scan1(const int* __restrict__ deg, int* __restrict__ bsum, int N){
  int t = threadIdx.x;
  int base = blockIdx.x*1024 + t*4;
  int s = 0;
  #pragma unroll
  for (int i=0;i<4;i++){ int idx=base+i; if (idx<N) s += deg[idx]; }
  __shared__ int ls[256];
  ls[t]=s; __syncthreads();
  for (int o=128;o>0;o>>=1){ if (t<o) ls[t]+=ls[t+o]; __syncthreads(); }
  if (t==0) bsum[blockIdx.x]=ls[0];
}

__global__ void k_scan2(int* __restrict__ bsum, int nb, int* __restrict__ ptr, int N, int E){
  int l = threadIdx.x;
  int v = (l<nb)? bsum[l] : 0;
  int x = v;
  #pragma unroll
  for (int o=1;o<64;o<<=1){ int y = __shfl_up(x,o); if (l>=o) x += y; }
  if (l<nb) bsum[l] = x - v;   // exclusive
  if (l==0) ptr[N] = E;
}

__global__ void k_scan3(const int* __restrict__ deg, const int* __restrict__ bsum,
                        int* __restrict__ ptr, int* __restrict__ cur, int N){
  int t = threadIdx.x;
  int base = blockIdx.x*1024 + t*4;
  int v[4]; int s=0;
  #pragma unroll
  for (int i=0;i<4;i++){ int idx=base+i; v[i] = (idx<N)? deg[idx] : 0; s += v[i]; }
  __shared__ int ls[256];
  ls[t]=s; __syncthreads();
  for (int o=1;o<256;o<<=1){
    int y = (t>=o)? ls[t-o] : 0;
    __syncthreads();
    ls[t] += y;
    __syncthreads();
  }
  int p = ls[t] - s + bsum[blockIdx.x];
  #pragma unroll
  for (int i=0;i<4;i++){
    int idx=base+i;
    if (idx<N){ ptr[idx]=p; cur[idx]=p; }
    p += v[i];
  }
}

__global__ void k_fill(const int* __restrict__ src, const int* __restrict__ dst,
                       int* __restrict__ cur, int* __restrict__ srcs, int E){
  int i = blockIdx.x*blockDim.x + threadIdx.x;
  if (i < E){
    int pos = atomicAdd(&cur[dst[i]], 1);
    srcs[pos] = src[i];
  }
}

// ---- Fused GEMM: wave = 64-col panel of W held in VGPRs, x-row via uniform
// (scalar) loads feeding v_fmac. NP=3: [W1 head0 | W1 head1 | skipW].
// NP=2: [W2 head0 | W2 head1]. Also computes attention dots per head.
template<int NP>
__global__ void k_gemm(const float* __restrict__ X, const float* __restrict__ Wm,
                       const float* __restrict__ Wsk, const float* __restrict__ att_s,
                       const float* __restrict__ att_d, float* __restrict__ Hout,
                       float* __restrict__ skv, float* __restrict__ a_s,
                       float* __restrict__ a_d, int N){
  int lane = threadIdx.x & 63;
  int p = threadIdx.x >> 6;      // panel id (wave-uniform)
  // load this wave's 64x64 weight panel into registers
  float w[64];
  const float* wb; int stride;
  if (p < 2){ wb = Wm + p*64 + lane; stride = 128; }
  else      { wb = Wsk + lane;       stride = 64;  }
  #pragma unroll
  for (int k=0;k<64;k++) w[k] = wb[(size_t)k*stride];
  float asv = 0.f, adv = 0.f;
  if (p < 2){ asv = att_s[p*64+lane]; adv = att_d[p*64+lane]; }

  int r0 = blockIdx.x * 32;
  for (int rr = 0; rr < 32; rr += 2){
    int r = r0 + rr;
    if (r >= N) break;
    int rB = (r+1 < N) ? r+1 : r;
    const float4* x0 = (const float4*)(X + (size_t)r *64);
    const float4* x1 = (const float4*)(X + (size_t)rB*64);
    float accA0=0.f, accA1=0.f, accB0=0.f, accB1=0.f;
    #pragma unroll
    for (int k4=0;k4<16;k4+=2){
      float4 u0 = x0[k4], u1 = x0[k4+1];
      float4 v0 = x1[k4], v1 = x1[k4+1];
      accA0 = fmaf(u0.x, w[4*k4+0], accA0);
      accA0 = fmaf(u0.y, w[4*k4+1], accA0);
      accA0 = fmaf(u0.z, w[4*k4+2], accA0);
      accA0 = fmaf(u0.w, w[4*k4+3], accA0);
      accA1 = fmaf(u1.x, w[4*k4+4], accA1);
      accA1 = fmaf(u1.y, w[4*k4+5], accA1);
      accA1 = fmaf(u1.z, w[4*k4+6], accA1);
      accA1 = fmaf(u1.w, w[4*k4+7], accA1);
      accB0 = fmaf(v0.x, w[4*k4+0], accB0);
      accB0 = fmaf(v0.y, w[4*k4+1], accB0);
      accB0 = fmaf(v0.z, w[4*k4+2], accB0);
      accB0 = fmaf(v0.w, w[4*k4+3], accB0);
      accB1 = fmaf(v1.x, w[4*k4+4], accB1);
      accB1 = fmaf(v1.y, w[4*k4+5], accB1);
      accB1 = fmaf(v1.z, w[4*k4+6], accB1);
      accB1 = fmaf(v1.w, w[4*k4+7], accB1);
    }
    float accA = accA0 + accA1;
    float accB = accB0 + accB1;
    // epilogue row r
    if (p < 2){
      Hout[(size_t)r*128 + p*64 + lane] = accA;
      float ps = accA*asv, pd = accA*adv;
      #pragma unroll
      for (int o=32;o>0;o>>=1){ ps += __shfl_xor(ps,o); pd += __shfl_xor(pd,o); }
      if (lane==0){ a_s[2*r+p] = ps; a_d[2*r+p] = pd; }
    } else {
      skv[(size_t)r*64 + lane] = accA;
    }
    // epilogue row r+1
    if (r+1 < N){
      if (p < 2){
        Hout[(size_t)(r+1)*128 + p*64 + lane] = accB;
        float ps = accB*asv, pd = accB*adv;
        #pragma unroll
        for (int o=32;o>0;o>>=1){ ps += __shfl_xor(ps,o); pd += __shfl_xor(pd,o); }
        if (lane==0){ a_s[2*(r+1)+p] = ps; a_d[2*(r+1)+p] = pd; }
      } else {
        skv[(size_t)(r+1)*64 + lane] = accB;
      }
    }
  }
}

// ---- GAT aggregation: one wave per node, single pass (no max-shift).
// Chunk of 64 edges: lane-parallel weights -> per-wave LDS -> uniform-broadcast
// message fma loop.
__global__ void k_agg(const float* __restrict__ Hbig, const float* __restrict__ a_s,
                      const float* __restrict__ a_d, const int* __restrict__ ptr,
                      const int* __restrict__ srcs, const float* __restrict__ bias,
                      float* __restrict__ out, int N){
  __shared__ float4 cbuf[256];           // 4 waves * 64 entries
  int tid = threadIdx.x;
  int wid = (blockIdx.x*blockDim.x + tid) >> 6;
  int lane = tid & 63;
  float4* mybuf = cbuf + (tid >> 6)*64;
  if (wid >= N) return;
  int n = wid;
  const float2* H2  = (const float2*)Hbig;
  const float2* AS2 = (const float2*)a_s;
  float2 adv = ((const float2*)a_d)[n];
  float2 asv = AS2[n];
  int e0 = ptr[n], e1 = ptr[n+1];
  // self-loop
  float w0 = __expf(lrelu(asv.x + adv.x));
  float w1 = __expf(lrelu(asv.y + adv.y));
  float2 hv = H2[(size_t)n*64 + lane];
  float wsel = (lane < 32) ? w0 : w1;
  float acc0 = hv.x*wsel, acc1 = hv.y*wsel;
  float d0 = 0.f, d1 = 0.f;
  for (int base = e0; base < e1; base += 64){
    int i = base + lane;
    float e_0 = 0.f, e_1 = 0.f; int sv = 0;
    if (i < e1){
      sv = srcs[i];
      float2 av = AS2[sv];
      e_0 = __expf(lrelu(av.x + adv.x));
      e_1 = __expf(lrelu(av.y + adv.y));
    }
    d0 += e_0; d1 += e_1;
    float4 pk; pk.x = __int_as_float(sv); pk.y = e_0; pk.z = e_1; pk.w = 0.f;
    mybuf[lane] = pk;
    int cnt = min(64, e1 - base);
    #pragma unroll 4
    for (int j = 0; j < cnt; j++){
      float4 c = mybuf[j];                        // wave-uniform broadcast read
      int sj = __float_as_int(c.x);
      float2 h2 = H2[(size_t)sj*64 + lane];
      float wss = (lane < 32) ? c.y : c.z;
      acc0 = fmaf(h2.x, wss, acc0);
      acc1 = fmaf(h2.y, wss, acc1);
    }
  }
  #pragma unroll
  for (int o=32;o>0;o>>=1){ d0 += __shfl_xor(d0,o); d1 += __shfl_xor(d1,o); }
  d0 += w0; d1 += w1;
  float dsel = (lane < 32) ? d0 : d1;
  acc0 /= dsel; acc1 /= dsel;
  // head mean: lane l (<32) pairs with lane l+32 (head 1, same channels)
  float o0 = 0.5f*(acc0 + __shfl_xor(acc0, 32));
  float o1 = 0.5f*(acc1 + __shfl_xor(acc1, 32));
  if (lane < 32){
    float2 res; res.x = o0 + bias[2*lane]; res.y = o1 + bias[2*lane+1];
    ((float2*)out)[(size_t)n*32 + lane] = res;
  }
}

// ---- BN stats: per-channel sum / sumsq ----
__global__ void k_bnstats(const float* __restrict__ X, float* __restrict__ part, int N){
  int t = threadIdx.x; int c = t & 63; int sub = t >> 6;
  float s = 0.f, s2 = 0.f;
  for (int r = blockIdx.x*4 + sub; r < N; r += gridDim.x*4){
    float v = X[(size_t)r*64 + c];
    s += v; s2 = fmaf(v, v, s2);
  }
  __shared__ float ls[256], lq[256];
  ls[t] = s; lq[t] = s2; __syncthreads();
  if (t < 64){
    s  = ls[t] + ls[t+64] + ls[t+128] + ls[t+192];
    s2 = lq[t] + lq[t+64] + lq[t+128] + lq[t+192];
    atomicAdd(&part[t], s);
    atomicAdd(&part[64+t], s2);
  }
}

__global__ void k_bnfinal(const float* __restrict__ part, const float* __restrict__ gamma,
                          const float* __restrict__ beta, float* __restrict__ bnb, int N){
  int c = threadIdx.x;
  float mu  = part[c] / (float)N;
  float var = part[64+c] / (float)N - mu*mu;
  var = fmaxf(var, 0.f);
  float sc = gamma[c] * rsqrtf(var + 1e-5f);
  bnb[c] = sc;
  bnb[64+c] = beta[c] - mu*sc;
}

// ---- hmid = gelu(bn(g1) + skip + skipb) ----
__global__ void k_fuse1(const float* __restrict__ g1, const float* __restrict__ bn,
                        const float* __restrict__ skip, const float* __restrict__ skipb,
                        float* __restrict__ hmid, int total){
  int i = blockIdx.x*blockDim.x + threadIdx.x;
  if (i < total){
    int c = i & 63;
    float v = fmaf(g1[i], bn[c], bn[64+c]) + skip[i] + skipb[c];
    hmid[i] = gelu_tanh(v);
  }
}

// ---- final: gelu(bn(g2)+hmid), pooled sums per batch (batch_index sorted) ----
__global__ void k_fusepool(const float* __restrict__ g2, const float* __restrict__ bn,
                           const float* __restrict__ hmid, const int* __restrict__ batch,
                           float* __restrict__ pool, float* __restrict__ cnt, int N){
  int t = threadIdx.x; int c = t & 63; int sub = t >> 6;
  int r0 = blockIdx.x*64;
  float scale = bn[c], shift = bn[64+c];
  float acc = 0.f, ca = 0.f; int curb = -1;
  for (int r = r0 + sub; r < N && r < r0 + 64; r += 4){
    int b = batch[r];
    if (b != curb){
      if (curb >= 0){
        atomicAdd(&pool[curb*64 + c], acc);
        if (c == 0) atomicAdd(&cnt[curb], ca);
      }
      acc = 0.f; ca = 0.f; curb = b;
    }
    float v = gelu_tanh(fmaf(g2[(size_t)r*64 + c], scale, shift) + hmid[(size_t)r*64 + c]);
    acc += v; ca += 1.f;
  }
  if (curb >= 0){
    atomicAdd(&pool[curb*64 + c], acc);
    if (c == 0) atomicAdd(&cnt[curb], ca);
  }
}

__global__ void k_out(const float* __restrict__ pool, const float* __restrict__ cnt,
                      float* __restrict__ out, int M){
  int i = blockIdx.x*blockDim.x + threadIdx.x;
  if (i < M) out[i] = pool[i] / fmaxf(cnt[i>>6], 1.f);
}

extern "C" void kernel_launch(void* const* d_in, const int* in_sizes, int n_in,
                              void* d_out, int out_size, void* d_ws, size_t ws_size,
                              hipStream_t stream) {
  const float* x     = (const float*)d_in[0];
  const int*   ei    = (const int*)  d_in[1];
  const int*   batch = (const int*)  d_in[2];
  const float* W1    = (const float*)d_in[3];
  const float* as1   = (const float*)d_in[4];
  const float* ad1   = (const float*)d_in[5];
  const float* b1    = (const float*)d_in[6];
  const float* skW   = (const float*)d_in[7];
  const float* skb   = (const float*)d_in[8];
  const float* gm1   = (const float*)d_in[9];
  const float* bt1   = (const float*)d_in[10];
  const float* W2    = (const float*)d_in[11];
  const float* as2   = (const float*)d_in[12];
  const float* ad2   = (const float*)d_in[13];
  const float* b2    = (const float*)d_in[14];
  const float* gm2   = (const float*)d_in[15];
  const float* bt2   = (const float*)d_in[16];

  int N = in_sizes[2];
  int E = in_sizes[1] / 2;
  const int* esrc = ei;
  const int* edst = ei + E;

  char* wp = (char*)d_ws;
  size_t off = 0;
  auto alloc = [&](size_t bytes)->void*{
    off = (off + 255) & ~(size_t)255;
    void* p = wp + off;
    off += bytes;
    return p;
  };
  int*   deg  = (int*)  alloc((size_t)N*4);
  int*   ptr  = (int*)  alloc((size_t)(N+1)*4);
  int*   cur  = (int*)  alloc((size_t)N*4);
  int*   bsum = (int*)  alloc(64*4);
  int*   srcs = (int*)  alloc((size_t)E*4);
  float* hbig = (float*)alloc((size_t)N*128*4);
  float* a_s  = (float*)alloc((size_t)N*2*4);
  float* a_d  = (float*)alloc((size_t)N*2*4);
  float* gout = (float*)alloc((size_t)N*64*4);   // GAT raw output (both layers)
  float* skv  = (float*)alloc((size_t)N*64*4);   // x @ skipW
  float* hmid = (float*)alloc((size_t)N*64*4);   // layer-1 final output
  float* zz   = (float*)alloc((size_t)(128+128+4096+64)*4); // zero zone
  float* part1 = zz;
  float* part2 = zz + 128;
  float* pool  = zz + 256;
  float* cnt   = zz + 256 + 4096;
  float* bnb1 = (float*)alloc(128*4);
  float* bnb2 = (float*)alloc(128*4);

  hipMemsetAsync(deg, 0, (size_t)N*4, stream);
  hipMemsetAsync(zz, 0, (size_t)(128+128+4096+64)*4, stream);

  const int TB = 256;
  int egrid = (E + TB - 1) / TB;
  int nch = (N + 1023) / 1024;
  int gg = (N + 31) / 32;

  // CSR build
  k_count<<<egrid, TB, 0, stream>>>(edst, deg, E);
  k_scan1<<<nch, 256, 0, stream>>>(deg, bsum, N);
  k_scan2<<<1, 64, 0, stream>>>(bsum, nch, ptr, N, E);
  k_scan3<<<nch, 256, 0, stream>>>(deg, bsum, ptr, cur, N);
  k_fill<<<egrid, TB, 0, stream>>>(esrc, edst, cur, srcs, E);

  // layer 1 (W1 + skip + att fused)
  k_gemm<3><<<gg, 192, 0, stream>>>(x, W1, skW, as1, ad1, hbig, skv, a_s, a_d, N);
  k_agg<<<(N+3)/4, 256, 0, stream>>>(hbig, a_s, a_d, ptr, srcs, b1, gout, N);
  k_bnstats<<<256, 256, 0, stream>>>(gout, part1, N);
  k_bnfinal<<<1, 64, 0, stream>>>(part1, gm1, bt1, bnb1, N);
  k_fuse1<<<(N*64 + 255)/256, 256, 0, stream>>>(gout, bnb1, skv, skb, hmid, N*64);

  // layer 2
  k_gemm<2><<<gg, 128, 0, stream>>>(hmid, W2, nullptr, as2, ad2, hbig, nullptr, a_s, a_d, N);
  k_agg<<<(N+3)/4, 256, 0, stream>>>(hbig, a_s, a_d, ptr, srcs, b2, gout, N);
  k_bnstats<<<256, 256, 0, stream>>>(gout, part2, N);
  k_bnfinal<<<1, 64, 0, stream>>>(part2, gm2, bt2, bnb2, N);

  // fuse + pool
  k_fusepool<<<(N+63)/64, 256, 0, stream>>>(gout, bnb2, hmid, batch, pool, cnt, N);
  k_out<<<(out_size + 255)/256, 256, 0, stream>>>(pool, cnt, (float*)d_out, out_size);
}

// Round 3
// 579.238 us; speedup vs baseline: 1.5326x; 1.0684x over previous
//
#include <hip/hip_runtime.h>
#include <math.h>

// GraphBlock: 2x GATConv(H=2 heads, C=64, concat=False) + BN(train) + GELU + skip + mean-pool
// N=50000, E=1.6M, F_IN=C=64, B=64

__device__ __forceinline__ float lrelu(float x){ return x > 0.f ? x : 0.2f*x; }
__device__ __forceinline__ float gelu_tanh(float x){
  const float k0 = 0.7978845608028654f; // sqrt(2/pi)
  const float k1 = 0.044715f;
  float t = tanhf(k0 * fmaf(k1*x*x, x, x));
  return 0.5f*x*(1.f + t);
}

// ---- CSR build ----
__global__ void k_count(const int* __restrict__ dst, int* __restrict__ deg, int E){
  int i = blockIdx.x*blockDim.x + threadIdx.x;
  if (i < E) atomicAdd(&deg[dst[i]], 1);
}

__global__ void k_scan1(const int* __restrict__ deg, int* __restrict__ bsum, int N){
  int t = threadIdx.x;
  int base = blockIdx.x*1024 + t*4;
  int s = 0;
  #pragma unroll
  for (int i=0;i<4;i++){ int idx=base+i; if (idx<N) s += deg[idx]; }
  __shared__ int ls[256];
  ls[t]=s; __syncthreads();
  for (int o=128;o>0;o>>=1){ if (t<o) ls[t]+=ls[t+o]; __syncthreads(); }
  if (t==0) bsum[blockIdx.x]=ls[0];
}

__global__ void k_scan2(int* __restrict__ bsum, int nb, int* __restrict__ ptr, int N, int E){
  int l = threadIdx.x;
  int v = (l<nb)? bsum[l] : 0;
  int x = v;
  #pragma unroll
  for (int o=1;o<64;o<<=1){ int y = __shfl_up(x,o); if (l>=o) x += y; }
  if (l<nb) bsum[l] = x - v;   // exclusive
  if (l==0) ptr[N] = E;
}

__global__ void k_scan3(const int* __restrict__ deg, const int* __restrict__ bsum,
                        int* __restrict__ ptr, int* __restrict__ cur, int N){
  int t = threadIdx.x;
  int base = blockIdx.x*1024 + t*4;
  int v[4]; int s=0;
  #pragma unroll
  for (int i=0;i<4;i++){ int idx=base+i; v[i] = (idx<N)? deg[idx] : 0; s += v[i]; }
  __shared__ int ls[256];
  ls[t]=s; __syncthreads();
  for (int o=1;o<256;o<<=1){
    int y = (t>=o)? ls[t-o] : 0;
    __syncthreads();
    ls[t] += y;
    __syncthreads();
  }
  int p = ls[t] - s + bsum[blockIdx.x];
  #pragma unroll
  for (int i=0;i<4;i++){
    int idx=base+i;
    if (idx<N){ ptr[idx]=p; cur[idx]=p; }
    p += v[i];
  }
}

// XCD-partitioned fill: slice s (= blockIdx%8, matching the round-robin
// block->XCD mapping) owns dst range [s*nps, (s+1)*nps). Each slice's blocks
// stream the whole edge list (coalesced) and scatter-store only into the
// slice's contiguous region of srcs -> lines stay in ONE XCD's L2 (kills the
// 16x write amplification seen in R2: WRITE_SIZE 101MB for a 6.4MB array).
#define NSLICE 8
__global__ void k_fill(const int* __restrict__ src, const int* __restrict__ dst,
                       int* __restrict__ cur, int* __restrict__ srcs, int E,
                       int nps, int bps){
  int slice = blockIdx.x & (NSLICE-1);
  int j     = blockIdx.x >> 3;
  int lo = slice * nps;
  int hi = lo + nps;
  int per = (E + bps - 1) / bps;
  int s0 = j * per;
  int s1 = min(E, s0 + per);
  for (int i = s0 + threadIdx.x; i < s1; i += blockDim.x){
    int d = dst[i];
    if (d >= lo && d < hi){
      int pos = atomicAdd(&cur[d], 1);
      srcs[pos] = src[i];
    }
  }
}

// ---- Fused GEMM: wave = 64-col panel of W held in VGPRs, x-row via float4
// loads feeding v_fmac. NP=3: [W1 head0 | W1 head1 | skipW].
// NP=2: [W2 head0 | W2 head1]. Also computes attention dots per head.
template<int NP>
__global__ void k_gemm(const float* __restrict__ X, const float* __restrict__ Wm,
                       const float* __restrict__ Wsk, const float* __restrict__ att_s,
                       const float* __restrict__ att_d, float* __restrict__ Hout,
                       float* __restrict__ skv, float* __restrict__ a_s,
                       float* __restrict__ a_d, int N){
  int lane = threadIdx.x & 63;
  int p = threadIdx.x >> 6;      // panel id (wave-uniform)
  // load this wave's 64x64 weight panel into registers
  float w[64];
  const float* wb; int stride;
  if (p < 2){ wb = Wm + p*64 + lane; stride = 128; }
  else      { wb = Wsk + lane;       stride = 64;  }
  #pragma unroll
  for (int k=0;k<64;k++) w[k] = wb[(size_t)k*stride];
  float asv = 0.f, adv = 0.f;
  if (p < 2){ asv = att_s[p*64+lane]; adv = att_d[p*64+lane]; }

  int r0 = blockIdx.x * 32;
  for (int rr = 0; rr < 32; rr += 2){
    int r = r0 + rr;
    if (r >= N) break;
    int rB = (r+1 < N) ? r+1 : r;
    const float4* x0 = (const float4*)(X + (size_t)r *64);
    const float4* x1 = (const float4*)(X + (size_t)rB*64);
    float accA0=0.f, accA1=0.f, accB0=0.f, accB1=0.f;
    #pragma unroll
    for (int k4=0;k4<16;k4+=2){
      float4 u0 = x0[k4], u1 = x0[k4+1];
      float4 v0 = x1[k4], v1 = x1[k4+1];
      accA0 = fmaf(u0.x, w[4*k4+0], accA0);
      accA0 = fmaf(u0.y, w[4*k4+1], accA0);
      accA0 = fmaf(u0.z, w[4*k4+2], accA0);
      accA0 = fmaf(u0.w, w[4*k4+3], accA0);
      accA1 = fmaf(u1.x, w[4*k4+4], accA1);
      accA1 = fmaf(u1.y, w[4*k4+5], accA1);
      accA1 = fmaf(u1.z, w[4*k4+6], accA1);
      accA1 = fmaf(u1.w, w[4*k4+7], accA1);
      accB0 = fmaf(v0.x, w[4*k4+0], accB0);
      accB0 = fmaf(v0.y, w[4*k4+1], accB0);
      accB0 = fmaf(v0.z, w[4*k4+2], accB0);
      accB0 = fmaf(v0.w, w[4*k4+3], accB0);
      accB1 = fmaf(v1.x, w[4*k4+4], accB1);
      accB1 = fmaf(v1.y, w[4*k4+5], accB1);
      accB1 = fmaf(v1.z, w[4*k4+6], accB1);
      accB1 = fmaf(v1.w, w[4*k4+7], accB1);
    }
    float accA = accA0 + accA1;
    float accB = accB0 + accB1;
    // epilogue row r
    if (p < 2){
      Hout[(size_t)r*128 + p*64 + lane] = accA;
      float ps = accA*asv, pd = accA*adv;
      #pragma unroll
      for (int o=32;o>0;o>>=1){ ps += __shfl_xor(ps,o); pd += __shfl_xor(pd,o); }
      if (lane==0){ a_s[2*r+p] = ps; a_d[2*r+p] = pd; }
    } else {
      skv[(size_t)r*64 + lane] = accA;
    }
    // epilogue row r+1
    if (r+1 < N){
      if (p < 2){
        Hout[(size_t)(r+1)*128 + p*64 + lane] = accB;
        float ps = accB*asv, pd = accB*adv;
        #pragma unroll
        for (int o=32;o>0;o>>=1){ ps += __shfl_xor(ps,o); pd += __shfl_xor(pd,o); }
        if (lane==0){ a_s[2*(r+1)+p] = ps; a_d[2*(r+1)+p] = pd; }
      } else {
        skv[(size_t)(r+1)*64 + lane] = accB;
      }
    }
  }
}

// ---- GAT aggregation: one wave per node, single pass (no max-shift).
// Chunk of 64 edges: lane-parallel weights -> per-wave LDS -> uniform-broadcast
// message fma loop.
__global__ void k_agg(const float* __restrict__ Hbig, const float* __restrict__ a_s,
                      const float* __restrict__ a_d, const int* __restrict__ ptr,
                      const int* __restrict__ srcs, const float* __restrict__ bias,
                      float* __restrict__ out, int N){
  __shared__ float4 cbuf[256];           // 4 waves * 64 entries
  int tid = threadIdx.x;
  int wid = (blockIdx.x*blockDim.x + tid) >> 6;
  int lane = tid & 63;
  float4* mybuf = cbuf + (tid >> 6)*64;
  if (wid >= N) return;
  int n = wid;
  const float2* H2  = (const float2*)Hbig;
  const float2* AS2 = (const float2*)a_s;
  float2 adv = ((const float2*)a_d)[n];
  float2 asv = AS2[n];
  int e0 = ptr[n], e1 = ptr[n+1];
  // self-loop
  float w0 = __expf(lrelu(asv.x + adv.x));
  float w1 = __expf(lrelu(asv.y + adv.y));
  float2 hv = H2[(size_t)n*64 + lane];
  float wsel = (lane < 32) ? w0 : w1;
  float acc0 = hv.x*wsel, acc1 = hv.y*wsel;
  float d0 = 0.f, d1 = 0.f;
  for (int base = e0; base < e1; base += 64){
    int i = base + lane;
    float e_0 = 0.f, e_1 = 0.f; int sv = 0;
    if (i < e1){
      sv = srcs[i];
      float2 av = AS2[sv];
      e_0 = __expf(lrelu(av.x + adv.x));
      e_1 = __expf(lrelu(av.y + adv.y));
    }
    d0 += e_0; d1 += e_1;
    float4 pk; pk.x = __int_as_float(sv); pk.y = e_0; pk.z = e_1; pk.w = 0.f;
    mybuf[lane] = pk;
    int cnt = min(64, e1 - base);
    #pragma unroll 4
    for (int j = 0; j < cnt; j++){
      float4 c = mybuf[j];                        // wave-uniform broadcast read
      int sj = __float_as_int(c.x);
      float2 h2 = H2[(size_t)sj*64 + lane];
      float wss = (lane < 32) ? c.y : c.z;
      acc0 = fmaf(h2.x, wss, acc0);
      acc1 = fmaf(h2.y, wss, acc1);
    }
  }
  #pragma unroll
  for (int o=32;o>0;o>>=1){ d0 += __shfl_xor(d0,o); d1 += __shfl_xor(d1,o); }
  d0 += w0; d1 += w1;
  float dsel = (lane < 32) ? d0 : d1;
  acc0 /= dsel; acc1 /= dsel;
  // head mean: lane l (<32) pairs with lane l+32 (head 1, same channels)
  float o0 = 0.5f*(acc0 + __shfl_xor(acc0, 32));
  float o1 = 0.5f*(acc1 + __shfl_xor(acc1, 32));
  if (lane < 32){
    float2 res; res.x = o0 + bias[2*lane]; res.y = o1 + bias[2*lane+1];
    ((float2*)out)[(size_t)n*32 + lane] = res;
  }
}

// ---- BN stats: per-channel sum / sumsq ----
__global__ void k_bnstats(const float* __restrict__ X, float* __restrict__ part, int N){
  int t = threadIdx.x; int c = t & 63; int sub = t >> 6;
  float s = 0.f, s2 = 0.f;
  for (int r = blockIdx.x*4 + sub; r < N; r += gridDim.x*4){
    float v = X[(size_t)r*64 + c];
    s += v; s2 = fmaf(v, v, s2);
  }
  __shared__ float ls[256], lq[256];
  ls[t] = s; lq[t] = s2; __syncthreads();
  if (t < 64){
    s  = ls[t] + ls[t+64] + ls[t+128] + ls[t+192];
    s2 = lq[t] + lq[t+64] + lq[t+128] + lq[t+192];
    atomicAdd(&part[t], s);
    atomicAdd(&part[64+t], s2);
  }
}

__global__ void k_bnfinal(const float* __restrict__ part, const float* __restrict__ gamma,
                          const float* __restrict__ beta, float* __restrict__ bnb, int N){
  int c = threadIdx.x;
  float mu  = part[c] / (float)N;
  float var = part[64+c] / (float)N - mu*mu;
  var = fmaxf(var, 0.f);
  float sc = gamma[c] * rsqrtf(var + 1e-5f);
  bnb[c] = sc;
  bnb[64+c] = beta[c] - mu*sc;
}

// ---- hmid = gelu(bn(g1) + skip + skipb) ----
__global__ void k_fuse1(const float* __restrict__ g1, const float* __restrict__ bn,
                        const float* __restrict__ skip, const float* __restrict__ skipb,
                        float* __restrict__ hmid, int total){
  int i = blockIdx.x*blockDim.x + threadIdx.x;
  if (i < total){
    int c = i & 63;
    float v = fmaf(g1[i], bn[c], bn[64+c]) + skip[i] + skipb[c];
    hmid[i] = gelu_tanh(v);
  }
}

// ---- final: gelu(bn(g2)+hmid), pooled sums per batch (batch_index sorted) ----
__global__ void k_fusepool(const float* __restrict__ g2, const float* __restrict__ bn,
                           const float* __restrict__ hmid, const int* __restrict__ batch,
                           float* __restrict__ pool, float* __restrict__ cnt, int N){
  int t = threadIdx.x; int c = t & 63; int sub = t >> 6;
  int r0 = blockIdx.x*64;
  float scale = bn[c], shift = bn[64+c];
  float acc = 0.f, ca = 0.f; int curb = -1;
  for (int r = r0 + sub; r < N && r < r0 + 64; r += 4){
    int b = batch[r];
    if (b != curb){
      if (curb >= 0){
        atomicAdd(&pool[curb*64 + c], acc);
        if (c == 0) atomicAdd(&cnt[curb], ca);
      }
      acc = 0.f; ca = 0.f; curb = b;
    }
    float v = gelu_tanh(fmaf(g2[(size_t)r*64 + c], scale, shift) + hmid[(size_t)r*64 + c]);
    acc += v; ca += 1.f;
  }
  if (curb >= 0){
    atomicAdd(&pool[curb*64 + c], acc);
    if (c == 0) atomicAdd(&cnt[curb], ca);
  }
}

__global__ void k_out(const float* __restrict__ pool, const float* __restrict__ cnt,
                      float* __restrict__ out, int M){
  int i = blockIdx.x*blockDim.x + threadIdx.x;
  if (i < M) out[i] = pool[i] / fmaxf(cnt[i>>6], 1.f);
}

extern "C" void kernel_launch(void* const* d_in, const int* in_sizes, int n_in,
                              void* d_out, int out_size, void* d_ws, size_t ws_size,
                              hipStream_t stream) {
  const float* x     = (const float*)d_in[0];
  const int*   ei    = (const int*)  d_in[1];
  const int*   batch = (const int*)  d_in[2];
  const float* W1    = (const float*)d_in[3];
  const float* as1   = (const float*)d_in[4];
  const float* ad1   = (const float*)d_in[5];
  const float* b1    = (const float*)d_in[6];
  const float* skW   = (const float*)d_in[7];
  const float* skb   = (const float*)d_in[8];
  const float* gm1   = (const float*)d_in[9];
  const float* bt1   = (const float*)d_in[10];
  const float* W2    = (const float*)d_in[11];
  const float* as2   = (const float*)d_in[12];
  const float* ad2   = (const float*)d_in[13];
  const float* b2    = (const float*)d_in[14];
  const float* gm2   = (const float*)d_in[15];
  const float* bt2   = (const float*)d_in[16];

  int N = in_sizes[2];
  int E = in_sizes[1] / 2;
  const int* esrc = ei;
  const int* edst = ei + E;

  char* wp = (char*)d_ws;
  size_t off = 0;
  auto alloc = [&](size_t bytes)->void*{
    off = (off + 255) & ~(size_t)255;
    void* p = wp + off;
    off += bytes;
    return p;
  };
  int*   deg  = (int*)  alloc((size_t)N*4);
  int*   ptr  = (int*)  alloc((size_t)(N+1)*4);
  int*   cur  = (int*)  alloc((size_t)N*4);
  int*   bsum = (int*)  alloc(64*4);
  int*   srcs = (int*)  alloc((size_t)E*4);
  float* hbig = (float*)alloc((size_t)N*128*4);
  float* a_s  = (float*)alloc((size_t)N*2*4);
  float* a_d  = (float*)alloc((size_t)N*2*4);
  float* gout = (float*)alloc((size_t)N*64*4);   // GAT raw output (both layers)
  float* skv  = (float*)alloc((size_t)N*64*4);   // x @ skipW
  float* hmid = (float*)alloc((size_t)N*64*4);   // layer-1 final output
  float* zz   = (float*)alloc((size_t)(128+128+4096+64)*4); // zero zone
  float* part1 = zz;
  float* part2 = zz + 128;
  float* pool  = zz + 256;
  float* cnt   = zz + 256 + 4096;
  float* bnb1 = (float*)alloc(128*4);
  float* bnb2 = (float*)alloc(128*4);

  hipMemsetAsync(deg, 0, (size_t)N*4, stream);
  hipMemsetAsync(zz, 0, (size_t)(128+128+4096+64)*4, stream);

  const int TB = 256;
  int egrid = (E + TB - 1) / TB;
  int nch = (N + 1023) / 1024;
  int gg = (N + 31) / 32;

  // CSR build
  k_count<<<egrid, TB, 0, stream>>>(edst, deg, E);
  k_scan1<<<nch, 256, 0, stream>>>(deg, bsum, N);
  k_scan2<<<1, 64, 0, stream>>>(bsum, nch, ptr, N, E);
  k_scan3<<<nch, 256, 0, stream>>>(deg, bsum, ptr, cur, N);
  {
    int nps = (N + NSLICE - 1) / NSLICE;
    int bps = 256;                    // blocks per slice
    k_fill<<<NSLICE*bps, TB, 0, stream>>>(esrc, edst, cur, srcs, E, nps, bps);
  }

  // layer 1 (W1 + skip + att fused)
  k_gemm<3><<<gg, 192, 0, stream>>>(x, W1, skW, as1, ad1, hbig, skv, a_s, a_d, N);
  k_agg<<<(N+3)/4, 256, 0, stream>>>(hbig, a_s, a_d, ptr, srcs, b1, gout, N);
  k_bnstats<<<256, 256, 0, stream>>>(gout, part1, N);
  k_bnfinal<<<1, 64, 0, stream>>>(part1, gm1, bt1, bnb1, N);
  k_fuse1<<<(N*64 + 255)/256, 256, 0, stream>>>(gout, bnb1, skv, skb, hmid, N*64);

  // layer 2
  k_gemm<2><<<gg, 128, 0, stream>>>(hmid, W2, nullptr, as2, ad2, hbig, nullptr, a_s, a_d, N);
  k_agg<<<(N+3)/4, 256, 0, stream>>>(hbig, a_s, a_d, ptr, srcs, b2, gout, N);
  k_bnstats<<<256, 256, 0, stream>>>(gout, part2, N);
  k_bnfinal<<<1, 64, 0, stream>>>(part2, gm2, bt2, bnb2, N);

  // fuse + pool
  k_fusepool<<<(N+63)/64, 256, 0, stream>>>(gout, bnb2, hmid, batch, pool, cnt, N);
  k_out<<<(out_size + 255)/256, 256, 0, stream>>>(pool, cnt, (float*)d_out, out_size);
}

// Round 4
// 489.881 us; speedup vs baseline: 1.8121x; 1.1824x over previous
//
#include <hip/hip_runtime.h>
#include <math.h>

// GraphBlock: 2x GATConv(H=2 heads, C=64, concat=False) + BN(train) + GELU + skip + mean-pool
// N=50000, E=1.6M, F_IN=C=64, B=64

__device__ __forceinline__ float lrelu(float x){ return x > 0.f ? x : 0.2f*x; }
__device__ __forceinline__ float gelu_tanh(float x){
  const float k0 = 0.7978845608028654f; // sqrt(2/pi)
  const float k1 = 0.044715f;
  float t = tanhf(k0 * fmaf(k1*x*x, x, x));
  return 0.5f*x*(1.f + t);
}
__device__ __forceinline__ unsigned short f2bf(float f){
  unsigned int u = __float_as_uint(f);
  u = (u + 0x7fffu + ((u >> 16) & 1u)) >> 16;   // RNE
  return (unsigned short)u;
}

#define NSLICE 8

// ---- CSR build ----
// XCD-partitioned count: slice owns dst range -> deg lines home to one XCD L2.
__global__ void k_count(const int* __restrict__ dst, int* __restrict__ deg, int E,
                        int nps, int bps){
  int slice = blockIdx.x & (NSLICE-1);
  int j     = blockIdx.x >> 3;
  int lo = slice * nps, hi = lo + nps;
  int per = (E + bps - 1) / bps;
  int s0 = j * per;
  int s1 = min(E, s0 + per);
  for (int i = s0 + threadIdx.x; i < s1; i += blockDim.x){
    int d = dst[i];
    if (d >= lo && d < hi) atomicAdd(&deg[d], 1);
  }
}

__global__ void k_scan1(const int* __restrict__ deg, int* __restrict__ bsum, int N){
  int t = threadIdx.x;
  int base = blockIdx.x*1024 + t*4;
  int s = 0;
  #pragma unroll
  for (int i=0;i<4;i++){ int idx=base+i; if (idx<N) s += deg[idx]; }
  __shared__ int ls[256];
  ls[t]=s; __syncthreads();
  for (int o=128;o>0;o>>=1){ if (t<o) ls[t]+=ls[t+o]; __syncthreads(); }
  if (t==0) bsum[blockIdx.x]=ls[0];
}

__global__ void k_scan2(int* __restrict__ bsum, int nb, int* __restrict__ ptr, int N, int E){
  int l = threadIdx.x;
  int v = (l<nb)? bsum[l] : 0;
  int x = v;
  #pragma unroll
  for (int o=1;o<64;o<<=1){ int y = __shfl_up(x,o); if (l>=o) x += y; }
  if (l<nb) bsum[l] = x - v;   // exclusive
  if (l==0) ptr[N] = E;
}

__global__ void k_scan3(const int* __restrict__ deg, const int* __restrict__ bsum,
                        int* __restrict__ ptr, int* __restrict__ cur, int N){
  int t = threadIdx.x;
  int base = blockIdx.x*1024 + t*4;
  int v[4]; int s=0;
  #pragma unroll
  for (int i=0;i<4;i++){ int idx=base+i; v[i] = (idx<N)? deg[idx] : 0; s += v[i]; }
  __shared__ int ls[256];
  ls[t]=s; __syncthreads();
  for (int o=1;o<256;o<<=1){
    int y = (t>=o)? ls[t-o] : 0;
    __syncthreads();
    ls[t] += y;
    __syncthreads();
  }
  int p = ls[t] - s + bsum[blockIdx.x];
  #pragma unroll
  for (int i=0;i<4;i++){
    int idx=base+i;
    if (idx<N){ ptr[idx]=p; cur[idx]=p; }
    p += v[i];
  }
}

// XCD-partitioned fill (kills 16x scattered-store write amplification).
__global__ void k_fill(const int* __restrict__ src, const int* __restrict__ dst,
                       int* __restrict__ cur, int* __restrict__ srcs, int E,
                       int nps, int bps){
  int slice = blockIdx.x & (NSLICE-1);
  int j     = blockIdx.x >> 3;
  int lo = slice * nps;
  int hi = lo + nps;
  int per = (E + bps - 1) / bps;
  int s0 = j * per;
  int s1 = min(E, s0 + per);
  for (int i = s0 + threadIdx.x; i < s1; i += blockDim.x){
    int d = dst[i];
    if (d >= lo && d < hi){
      int pos = atomicAdd(&cur[d], 1);
      srcs[pos] = src[i];
    }
  }
}

// ---- Fused GEMM: wave = 64-col panel of W held in VGPRs. H stored as bf16
// (only consumer is k_agg's gather). NP=3: [W1 h0 | W1 h1 | skipW], NP=2: W2.
template<int NP>
__global__ void k_gemm(const float* __restrict__ X, const float* __restrict__ Wm,
                       const float* __restrict__ Wsk, const float* __restrict__ att_s,
                       const float* __restrict__ att_d, unsigned short* __restrict__ Hout,
                       float* __restrict__ skv, float* __restrict__ a_s,
                       float* __restrict__ a_d, int N){
  int lane = threadIdx.x & 63;
  int p = threadIdx.x >> 6;      // panel id (wave-uniform)
  float w[64];
  const float* wb; int stride;
  if (p < 2){ wb = Wm + p*64 + lane; stride = 128; }
  else      { wb = Wsk + lane;       stride = 64;  }
  #pragma unroll
  for (int k=0;k<64;k++) w[k] = wb[(size_t)k*stride];
  float asv = 0.f, adv = 0.f;
  if (p < 2){ asv = att_s[p*64+lane]; adv = att_d[p*64+lane]; }

  int r0 = blockIdx.x * 32;
  for (int rr = 0; rr < 32; rr += 2){
    int r = r0 + rr;
    if (r >= N) break;
    int rB = (r+1 < N) ? r+1 : r;
    const float4* x0 = (const float4*)(X + (size_t)r *64);
    const float4* x1 = (const float4*)(X + (size_t)rB*64);
    float accA0=0.f, accA1=0.f, accB0=0.f, accB1=0.f;
    #pragma unroll
    for (int k4=0;k4<16;k4+=2){
      float4 u0 = x0[k4], u1 = x0[k4+1];
      float4 v0 = x1[k4], v1 = x1[k4+1];
      accA0 = fmaf(u0.x, w[4*k4+0], accA0);
      accA0 = fmaf(u0.y, w[4*k4+1], accA0);
      accA0 = fmaf(u0.z, w[4*k4+2], accA0);
      accA0 = fmaf(u0.w, w[4*k4+3], accA0);
      accA1 = fmaf(u1.x, w[4*k4+4], accA1);
      accA1 = fmaf(u1.y, w[4*k4+5], accA1);
      accA1 = fmaf(u1.z, w[4*k4+6], accA1);
      accA1 = fmaf(u1.w, w[4*k4+7], accA1);
      accB0 = fmaf(v0.x, w[4*k4+0], accB0);
      accB0 = fmaf(v0.y, w[4*k4+1], accB0);
      accB0 = fmaf(v0.z, w[4*k4+2], accB0);
      accB0 = fmaf(v0.w, w[4*k4+3], accB0);
      accB1 = fmaf(v1.x, w[4*k4+4], accB1);
      accB1 = fmaf(v1.y, w[4*k4+5], accB1);
      accB1 = fmaf(v1.z, w[4*k4+6], accB1);
      accB1 = fmaf(v1.w, w[4*k4+7], accB1);
    }
    float accA = accA0 + accA1;
    float accB = accB0 + accB1;
    if (p < 2){
      Hout[(size_t)r*128 + p*64 + lane] = f2bf(accA);
      float ps = accA*asv, pd = accA*adv;
      #pragma unroll
      for (int o=32;o>0;o>>=1){ ps += __shfl_xor(ps,o); pd += __shfl_xor(pd,o); }
      if (lane==0){ a_s[2*r+p] = ps; a_d[2*r+p] = pd; }
    } else {
      skv[(size_t)r*64 + lane] = accA;
    }
    if (r+1 < N){
      if (p < 2){
        Hout[(size_t)(r+1)*128 + p*64 + lane] = f2bf(accB);
        float ps = accB*asv, pd = accB*adv;
        #pragma unroll
        for (int o=32;o>0;o>>=1){ ps += __shfl_xor(ps,o); pd += __shfl_xor(pd,o); }
        if (lane==0){ a_s[2*(r+1)+p] = ps; a_d[2*(r+1)+p] = pd; }
      } else {
        skv[(size_t)(r+1)*64 + lane] = accB;
      }
    }
  }
}

// ---- GAT aggregation: one wave per node, single pass (no max-shift).
// bf16-packed H gather: one dword/lane per edge (2 channels of this lane's head).
__global__ void k_agg(const unsigned short* __restrict__ Hp, const float* __restrict__ a_s,
                      const float* __restrict__ a_d, const int* __restrict__ ptr,
                      const int* __restrict__ srcs, const float* __restrict__ bias,
                      float* __restrict__ out, int N){
  __shared__ float4 cbuf[256];           // 4 waves * 64 entries
  int tid = threadIdx.x;
  int wid = (blockIdx.x*blockDim.x + tid) >> 6;
  int lane = tid & 63;
  float4* mybuf = cbuf + (tid >> 6)*64;
  if (wid >= N) return;
  int n = wid;
  const unsigned int* HP = (const unsigned int*)Hp;   // [N][64] dwords
  const float2* AS2 = (const float2*)a_s;
  float2 adv = ((const float2*)a_d)[n];
  float2 asv = AS2[n];
  int e0 = ptr[n], e1 = ptr[n+1];
  // self-loop
  float w0 = __expf(lrelu(asv.x + adv.x));
  float w1 = __expf(lrelu(asv.y + adv.y));
  unsigned int hw = HP[(size_t)n*64 + lane];
  float wsel = (lane < 32) ? w0 : w1;
  float acc0 = __uint_as_float(hw << 16) * wsel;
  float acc1 = __uint_as_float(hw & 0xffff0000u) * wsel;
  float d0 = 0.f, d1 = 0.f;
  for (int base = e0; base < e1; base += 64){
    int i = base + lane;
    float e_0 = 0.f, e_1 = 0.f; int sv = 0;
    if (i < e1){
      sv = srcs[i];
      float2 av = AS2[sv];
      e_0 = __expf(lrelu(av.x + adv.x));
      e_1 = __expf(lrelu(av.y + adv.y));
    }
    d0 += e_0; d1 += e_1;
    float4 pk; pk.x = __int_as_float(sv); pk.y = e_0; pk.z = e_1; pk.w = 0.f;
    mybuf[lane] = pk;
    int cnt = min(64, e1 - base);
    #pragma unroll 8
    for (int j = 0; j < cnt; j++){
      float4 c = mybuf[j];                        // wave-uniform broadcast read
      int sj = __float_as_int(c.x);
      unsigned int hj = HP[(size_t)sj*64 + lane];
      float wss = (lane < 32) ? c.y : c.z;
      acc0 = fmaf(__uint_as_float(hj << 16),        wss, acc0);
      acc1 = fmaf(__uint_as_float(hj & 0xffff0000u), wss, acc1);
    }
  }
  #pragma unroll
  for (int o=32;o>0;o>>=1){ d0 += __shfl_xor(d0,o); d1 += __shfl_xor(d1,o); }
  d0 += w0; d1 += w1;
  float dsel = (lane < 32) ? d0 : d1;
  acc0 /= dsel; acc1 /= dsel;
  // head mean: lane l (<32) pairs with lane l+32 (head 1, same channels)
  float o0 = 0.5f*(acc0 + __shfl_xor(acc0, 32));
  float o1 = 0.5f*(acc1 + __shfl_xor(acc1, 32));
  if (lane < 32){
    float2 res; res.x = o0 + bias[2*lane]; res.y = o1 + bias[2*lane+1];
    ((float2*)out)[(size_t)n*32 + lane] = res;
  }
}

// ---- BN stats: per-channel sum / sumsq ----
__global__ void k_bnstats(const float* __restrict__ X, float* __restrict__ part, int N){
  int t = threadIdx.x; int c = t & 63; int sub = t >> 6;
  float s = 0.f, s2 = 0.f;
  for (int r = blockIdx.x*4 + sub; r < N; r += gridDim.x*4){
    float v = X[(size_t)r*64 + c];
    s += v; s2 = fmaf(v, v, s2);
  }
  __shared__ float ls[256], lq[256];
  ls[t] = s; lq[t] = s2; __syncthreads();
  if (t < 64){
    s  = ls[t] + ls[t+64] + ls[t+128] + ls[t+192];
    s2 = lq[t] + lq[t+64] + lq[t+128] + lq[t+192];
    atomicAdd(&part[t], s);
    atomicAdd(&part[64+t], s2);
  }
}

__global__ void k_bnfinal(const float* __restrict__ part, const float* __restrict__ gamma,
                          const float* __restrict__ beta, float* __restrict__ bnb, int N){
  int c = threadIdx.x;
  float mu  = part[c] / (float)N;
  float var = part[64+c] / (float)N - mu*mu;
  var = fmaxf(var, 0.f);
  float sc = gamma[c] * rsqrtf(var + 1e-5f);
  bnb[c] = sc;
  bnb[64+c] = beta[c] - mu*sc;
}

// ---- hmid = gelu(bn(g1) + skip + skipb) ----
__global__ void k_fuse1(const float* __restrict__ g1, const float* __restrict__ bn,
                        const float* __restrict__ skip, const float* __restrict__ skipb,
                        float* __restrict__ hmid, int total){
  int i = blockIdx.x*blockDim.x + threadIdx.x;
  if (i < total){
    int c = i & 63;
    float v = fmaf(g1[i], bn[c], bn[64+c]) + skip[i] + skipb[c];
    hmid[i] = gelu_tanh(v);
  }
}

// ---- final: gelu(bn(g2)+hmid), pooled sums per batch (batch_index sorted) ----
__global__ void k_fusepool(const float* __restrict__ g2, const float* __restrict__ bn,
                           const float* __restrict__ hmid, const int* __restrict__ batch,
                           float* __restrict__ pool, float* __restrict__ cnt, int N){
  int t = threadIdx.x; int c = t & 63; int sub = t >> 6;
  int r0 = blockIdx.x*64;
  float scale = bn[c], shift = bn[64+c];
  float acc = 0.f, ca = 0.f; int curb = -1;
  for (int r = r0 + sub; r < N && r < r0 + 64; r += 4){
    int b = batch[r];
    if (b != curb){
      if (curb >= 0){
        atomicAdd(&pool[curb*64 + c], acc);
        if (c == 0) atomicAdd(&cnt[curb], ca);
      }
      acc = 0.f; ca = 0.f; curb = b;
    }
    float v = gelu_tanh(fmaf(g2[(size_t)r*64 + c], scale, shift) + hmid[(size_t)r*64 + c]);
    acc += v; ca += 1.f;
  }
  if (curb >= 0){
    atomicAdd(&pool[curb*64 + c], acc);
    if (c == 0) atomicAdd(&cnt[curb], ca);
  }
}

__global__ void k_out(const float* __restrict__ pool, const float* __restrict__ cnt,
                      float* __restrict__ out, int M){
  int i = blockIdx.x*blockDim.x + threadIdx.x;
  if (i < M) out[i] = pool[i] / fmaxf(cnt[i>>6], 1.f);
}

extern "C" void kernel_launch(void* const* d_in, const int* in_sizes, int n_in,
                              void* d_out, int out_size, void* d_ws, size_t ws_size,
                              hipStream_t stream) {
  const float* x     = (const float*)d_in[0];
  const int*   ei    = (const int*)  d_in[1];
  const int*   batch = (const int*)  d_in[2];
  const float* W1    = (const float*)d_in[3];
  const float* as1   = (const float*)d_in[4];
  const float* ad1   = (const float*)d_in[5];
  const float* b1    = (const float*)d_in[6];
  const float* skW   = (const float*)d_in[7];
  const float* skb   = (const float*)d_in[8];
  const float* gm1   = (const float*)d_in[9];
  const float* bt1   = (const float*)d_in[10];
  const float* W2    = (const float*)d_in[11];
  const float* as2   = (const float*)d_in[12];
  const float* ad2   = (const float*)d_in[13];
  const float* b2    = (const float*)d_in[14];
  const float* gm2   = (const float*)d_in[15];
  const float* bt2   = (const float*)d_in[16];

  int N = in_sizes[2];
  int E = in_sizes[1] / 2;
  const int* esrc = ei;
  const int* edst = ei + E;

  char* wp = (char*)d_ws;
  size_t off = 0;
  auto alloc = [&](size_t bytes)->void*{
    off = (off + 255) & ~(size_t)255;
    void* p = wp + off;
    off += bytes;
    return p;
  };
  int*   deg  = (int*)  alloc((size_t)N*4);
  int*   ptr  = (int*)  alloc((size_t)(N+1)*4);
  int*   cur  = (int*)  alloc((size_t)N*4);
  int*   bsum = (int*)  alloc(64*4);
  int*   srcs = (int*)  alloc((size_t)E*4);
  unsigned short* hpack = (unsigned short*)alloc((size_t)N*128*2);  // bf16 H
  float* a_s  = (float*)alloc((size_t)N*2*4);
  float* a_d  = (float*)alloc((size_t)N*2*4);
  float* gout = (float*)alloc((size_t)N*64*4);   // GAT raw output (both layers)
  float* skv  = (float*)alloc((size_t)N*64*4);   // x @ skipW
  float* hmid = (float*)alloc((size_t)N*64*4);   // layer-1 final output
  float* zz   = (float*)alloc((size_t)(128+128+4096+64)*4); // zero zone
  float* part1 = zz;
  float* part2 = zz + 128;
  float* pool  = zz + 256;
  float* cnt   = zz + 256 + 4096;
  float* bnb1 = (float*)alloc(128*4);
  float* bnb2 = (float*)alloc(128*4);

  hipMemsetAsync(deg, 0, (size_t)N*4, stream);
  hipMemsetAsync(zz, 0, (size_t)(128+128+4096+64)*4, stream);

  const int TB = 256;
  int nch = (N + 1023) / 1024;
  int gg = (N + 31) / 32;
  int nps = (N + NSLICE - 1) / NSLICE;
  int bps = 256;                    // blocks per slice

  // CSR build
  k_count<<<NSLICE*bps, TB, 0, stream>>>(edst, deg, E, nps, bps);
  k_scan1<<<nch, 256, 0, stream>>>(deg, bsum, N);
  k_scan2<<<1, 64, 0, stream>>>(bsum, nch, ptr, N, E);
  k_scan3<<<nch, 256, 0, stream>>>(deg, bsum, ptr, cur, N);
  k_fill<<<NSLICE*bps, TB, 0, stream>>>(esrc, edst, cur, srcs, E, nps, bps);

  // layer 1 (W1 + skip + att fused)
  k_gemm<3><<<gg, 192, 0, stream>>>(x, W1, skW, as1, ad1, hpack, skv, a_s, a_d, N);
  k_agg<<<(N+3)/4, 256, 0, stream>>>(hpack, a_s, a_d, ptr, srcs, b1, gout, N);
  k_bnstats<<<256, 256, 0, stream>>>(gout, part1, N);
  k_bnfinal<<<1, 64, 0, stream>>>(part1, gm1, bt1, bnb1, N);
  k_fuse1<<<(N*64 + 255)/256, 256, 0, stream>>>(gout, bnb1, skv, skb, hmid, N*64);

  // layer 2
  k_gemm<2><<<gg, 128, 0, stream>>>(hmid, W2, nullptr, as2, ad2, hpack, nullptr, a_s, a_d, N);
  k_agg<<<(N+3)/4, 256, 0, stream>>>(hpack, a_s, a_d, ptr, srcs, b2, gout, N);
  k_bnstats<<<256, 256, 0, stream>>>(gout, part2, N);
  k_bnfinal<<<1, 64, 0, stream>>>(part2, gm2, bt2, bnb2, N);

  // fuse + pool
  k_fusepool<<<(N+63)/64, 256, 0, stream>>>(gout, bnb2, hmid, batch, pool, cnt, N);
  k_out<<<(out_size + 255)/256, 256, 0, stream>>>(pool, cnt, (float*)d_out, out_size);
}

// Round 5
// 372.239 us; speedup vs baseline: 2.3848x; 1.3160x over previous
//
#include <hip/hip_runtime.h>
#include <math.h>

// GraphBlock: 2x GATConv(H=2 heads, C=64, concat=False) + BN(train) + GELU + skip + mean-pool
// N=50000, E=1.6M, F_IN=C=64, B=64

__device__ __forceinline__ float lrelu(float x){ return x > 0.f ? x : 0.2f*x; }
__device__ __forceinline__ float gelu_tanh(float x){
  const float k0 = 0.7978845608028654f; // sqrt(2/pi)
  const float k1 = 0.044715f;
  float t = tanhf(k0 * fmaf(k1*x*x, x, x));
  return 0.5f*x*(1.f + t);
}
__device__ __forceinline__ unsigned short f2bf(float f){
  unsigned int u = __float_as_uint(f);
  u = (u + 0x7fffu + ((u >> 16) & 1u)) >> 16;   // RNE
  return (unsigned short)u;
}

// ================= CSR build via 2-level bucket sort =================
// bucket = dst >> 7 (128 nodes per bucket, NB = ceil(N/128) <= 512)
// record = (src << 7) | (dst & 127)  -- src < 2^17, fits u32.

__global__ void p_hist(const int* __restrict__ dst, int* __restrict__ bhist,
                       int E, int NB){
  __shared__ int lh[512];
  for (int i = threadIdx.x; i < NB; i += blockDim.x) lh[i] = 0;
  __syncthreads();
  int stride = gridDim.x * blockDim.x;
  for (int i = blockIdx.x*blockDim.x + threadIdx.x; i < E; i += stride)
    atomicAdd(&lh[dst[i] >> 7], 1);
  __syncthreads();
  for (int i = threadIdx.x; i < NB; i += blockDim.x)
    if (lh[i]) atomicAdd(&bhist[i], lh[i]);
}

__global__ void p_scan(const int* __restrict__ bhist, int* __restrict__ boff,
                       int* __restrict__ bcur, int* __restrict__ ptr,
                       int NB, int N, int E){
  __shared__ int ls[512];
  int t = threadIdx.x;
  int v = (t < NB) ? bhist[t] : 0;
  ls[t] = v; __syncthreads();
  for (int o = 1; o < 512; o <<= 1){
    int y = (t >= o) ? ls[t-o] : 0;
    __syncthreads();
    ls[t] += y;
    __syncthreads();
  }
  int ex = ls[t] - v;
  if (t < NB){ boff[t] = ex; bcur[t] = ex; }
  if (t == 0){ boff[NB] = E; ptr[N] = E; }
}

#define BIN_CHUNK 8192
__global__ void p_bin(const int* __restrict__ src, const int* __restrict__ dst,
                      int* __restrict__ bcur, unsigned int* __restrict__ recs,
                      int E, int NB){
  __shared__ int lh[512];     // local hist, then local cursor
  __shared__ int lbase[512];  // claimed global base per bucket
  int c0 = blockIdx.x * BIN_CHUNK;
  int cnt = min(BIN_CHUNK, E - c0);
  if (cnt <= 0) return;
  int t = threadIdx.x;
  for (int i = t; i < NB; i += blockDim.x) lh[i] = 0;
  __syncthreads();
  for (int i = t; i < cnt; i += blockDim.x)
    atomicAdd(&lh[dst[c0+i] >> 7], 1);
  __syncthreads();
  for (int i = t; i < NB; i += blockDim.x){
    int c = lh[i];
    lbase[i] = (c > 0) ? atomicAdd(&bcur[i], c) : 0;
    lh[i] = 0;   // reuse as local cursor
  }
  __syncthreads();
  for (int i = t; i < cnt; i += blockDim.x){
    int d = dst[c0+i];
    int b = d >> 7;
    int p = atomicAdd(&lh[b], 1);
    recs[lbase[b] + p] = ((unsigned int)src[c0+i] << 7) | (unsigned int)(d & 127);
  }
}

// one block per bucket: counting-sort 128 local nodes; block exclusively owns
// its [r0,r1) window of srcs -> no cross-block line sharing (write amp ~1).
__global__ void p_csr(const unsigned int* __restrict__ recs, const int* __restrict__ boff,
                      int* __restrict__ ptr, int* __restrict__ srcs, int N){
  int b = blockIdx.x;
  int r0 = boff[b], r1 = boff[b+1];
  __shared__ int lh[128];
  int t = threadIdx.x;    // 256 threads
  if (t < 128) lh[t] = 0;
  __syncthreads();
  for (int i = r0 + t; i < r1; i += 256)
    atomicAdd(&lh[recs[i] & 127u], 1);
  __syncthreads();
  int mycnt = (t < 128) ? lh[t] : 0;
  for (int o = 1; o < 128; o <<= 1){
    int y = (t < 128 && t >= o) ? lh[t-o] : 0;
    __syncthreads();
    if (t < 128) lh[t] += y;
    __syncthreads();
  }
  if (t < 128){
    int excl = lh[t] - mycnt;
    int node = b*128 + t;
    if (node < N) ptr[node] = r0 + excl;
    lh[t] = excl;          // reuse as scatter cursor
  }
  __syncthreads();
  for (int i = r0 + t; i < r1; i += 256){
    unsigned int rec = recs[i];
    int j = rec & 127u;
    int p = atomicAdd(&lh[j], 1);
    srcs[r0 + p] = (int)(rec >> 7);
  }
}

// ---- Fused GEMM: wave = 64-col panel of W held in VGPRs (pinned via asm so
// the compiler can't demote to in-loop reloads; R4 showed VGPR=40 => demotion).
// NP=3: [W1 h0 | W1 h1 | skipW], NP=2: W2. H stored bf16 for k_agg's gather.
template<int NP>
__global__ void __launch_bounds__(192, 2)
k_gemm(const float* __restrict__ X, const float* __restrict__ Wm,
       const float* __restrict__ Wsk, const float* __restrict__ att_s,
       const float* __restrict__ att_d, unsigned short* __restrict__ Hout,
       float* __restrict__ skv, float* __restrict__ a_s,
       float* __restrict__ a_d, int N){
  int lane = threadIdx.x & 63;
  int p = threadIdx.x >> 6;      // panel id (wave-uniform)
  float w[64];
  const float* wb; int stride;
  if (p < 2){ wb = Wm + p*64 + lane; stride = 128; }
  else      { wb = Wsk + lane;       stride = 64;  }
  #pragma unroll
  for (int k=0;k<64;k++) w[k] = wb[(size_t)k*stride];
  #pragma unroll
  for (int k=0;k<64;k++) asm volatile("" : "+v"(w[k]));  // pin in VGPRs
  float asv = 0.f, adv = 0.f;
  if (p < 2){ asv = att_s[p*64+lane]; adv = att_d[p*64+lane]; }

  int r0 = blockIdx.x * 32;
  for (int rr = 0; rr < 32; rr += 2){
    int r = r0 + rr;
    if (r >= N) break;
    int rB = (r+1 < N) ? r+1 : r;
    const float4* x0 = (const float4*)(X + (size_t)r *64);
    const float4* x1 = (const float4*)(X + (size_t)rB*64);
    float accA0=0.f, accA1=0.f, accB0=0.f, accB1=0.f;
    #pragma unroll
    for (int k4=0;k4<16;k4+=2){
      float4 u0 = x0[k4], u1 = x0[k4+1];
      float4 v0 = x1[k4], v1 = x1[k4+1];
      accA0 = fmaf(u0.x, w[4*k4+0], accA0);
      accA0 = fmaf(u0.y, w[4*k4+1], accA0);
      accA0 = fmaf(u0.z, w[4*k4+2], accA0);
      accA0 = fmaf(u0.w, w[4*k4+3], accA0);
      accA1 = fmaf(u1.x, w[4*k4+4], accA1);
      accA1 = fmaf(u1.y, w[4*k4+5], accA1);
      accA1 = fmaf(u1.z, w[4*k4+6], accA1);
      accA1 = fmaf(u1.w, w[4*k4+7], accA1);
      accB0 = fmaf(v0.x, w[4*k4+0], accB0);
      accB0 = fmaf(v0.y, w[4*k4+1], accB0);
      accB0 = fmaf(v0.z, w[4*k4+2], accB0);
      accB0 = fmaf(v0.w, w[4*k4+3], accB0);
      accB1 = fmaf(v1.x, w[4*k4+4], accB1);
      accB1 = fmaf(v1.y, w[4*k4+5], accB1);
      accB1 = fmaf(v1.z, w[4*k4+6], accB1);
      accB1 = fmaf(v1.w, w[4*k4+7], accB1);
    }
    float accA = accA0 + accA1;
    float accB = accB0 + accB1;
    if (p < 2){
      Hout[(size_t)r*128 + p*64 + lane] = f2bf(accA);
      float ps = accA*asv, pd = accA*adv;
      #pragma unroll
      for (int o=32;o>0;o>>=1){ ps += __shfl_xor(ps,o); pd += __shfl_xor(pd,o); }
      if (lane==0){ a_s[2*r+p] = ps; a_d[2*r+p] = pd; }
    } else {
      skv[(size_t)r*64 + lane] = accA;
    }
    if (r+1 < N){
      if (p < 2){
        Hout[(size_t)(r+1)*128 + p*64 + lane] = f2bf(accB);
        float ps = accB*asv, pd = accB*adv;
        #pragma unroll
        for (int o=32;o>0;o>>=1){ ps += __shfl_xor(ps,o); pd += __shfl_xor(pd,o); }
        if (lane==0){ a_s[2*(r+1)+p] = ps; a_d[2*(r+1)+p] = pd; }
      } else {
        skv[(size_t)(r+1)*64 + lane] = accB;
      }
    }
  }
}

// ---- GAT aggregation: one wave per node, single pass (no max-shift).
// bf16-packed H gather: one dword/lane per edge (2 channels of this lane's head).
__global__ void k_agg(const unsigned short* __restrict__ Hp, const float* __restrict__ a_s,
                      const float* __restrict__ a_d, const int* __restrict__ ptr,
                      const int* __restrict__ srcs, const float* __restrict__ bias,
                      float* __restrict__ out, int N){
  __shared__ float4 cbuf[256];           // 4 waves * 64 entries
  int tid = threadIdx.x;
  int wid = (blockIdx.x*blockDim.x + tid) >> 6;
  int lane = tid & 63;
  float4* mybuf = cbuf + (tid >> 6)*64;
  if (wid >= N) return;
  int n = wid;
  const unsigned int* HP = (const unsigned int*)Hp;   // [N][64] dwords
  const float2* AS2 = (const float2*)a_s;
  float2 adv = ((const float2*)a_d)[n];
  float2 asv = AS2[n];
  int e0 = ptr[n], e1 = ptr[n+1];
  // self-loop
  float w0 = __expf(lrelu(asv.x + adv.x));
  float w1 = __expf(lrelu(asv.y + adv.y));
  unsigned int hw = HP[(size_t)n*64 + lane];
  float wsel = (lane < 32) ? w0 : w1;
  float acc0 = __uint_as_float(hw << 16) * wsel;
  float acc1 = __uint_as_float(hw & 0xffff0000u) * wsel;
  float d0 = 0.f, d1 = 0.f;
  for (int base = e0; base < e1; base += 64){
    int i = base + lane;
    float e_0 = 0.f, e_1 = 0.f; int sv = 0;
    if (i < e1){
      sv = srcs[i];
      float2 av = AS2[sv];
      e_0 = __expf(lrelu(av.x + adv.x));
      e_1 = __expf(lrelu(av.y + adv.y));
    }
    d0 += e_0; d1 += e_1;
    float4 pk; pk.x = __int_as_float(sv); pk.y = e_0; pk.z = e_1; pk.w = 0.f;
    mybuf[lane] = pk;
    int cnt = min(64, e1 - base);
    #pragma unroll 8
    for (int j = 0; j < cnt; j++){
      float4 c = mybuf[j];                        // wave-uniform broadcast read
      int sj = __float_as_int(c.x);
      unsigned int hj = HP[(size_t)sj*64 + lane];
      float wss = (lane < 32) ? c.y : c.z;
      acc0 = fmaf(__uint_as_float(hj << 16),        wss, acc0);
      acc1 = fmaf(__uint_as_float(hj & 0xffff0000u), wss, acc1);
    }
  }
  #pragma unroll
  for (int o=32;o>0;o>>=1){ d0 += __shfl_xor(d0,o); d1 += __shfl_xor(d1,o); }
  d0 += w0; d1 += w1;
  float dsel = (lane < 32) ? d0 : d1;
  acc0 /= dsel; acc1 /= dsel;
  // head mean: lane l (<32) pairs with lane l+32 (head 1, same channels)
  float o0 = 0.5f*(acc0 + __shfl_xor(acc0, 32));
  float o1 = 0.5f*(acc1 + __shfl_xor(acc1, 32));
  if (lane < 32){
    float2 res; res.x = o0 + bias[2*lane]; res.y = o1 + bias[2*lane+1];
    ((float2*)out)[(size_t)n*32 + lane] = res;
  }
}

// ---- BN stats: per-channel sum / sumsq ----
__global__ void k_bnstats(const float* __restrict__ X, float* __restrict__ part, int N){
  int t = threadIdx.x; int c = t & 63; int sub = t >> 6;
  float s = 0.f, s2 = 0.f;
  for (int r = blockIdx.x*4 + sub; r < N; r += gridDim.x*4){
    float v = X[(size_t)r*64 + c];
    s += v; s2 = fmaf(v, v, s2);
  }
  __shared__ float ls[256], lq[256];
  ls[t] = s; lq[t] = s2; __syncthreads();
  if (t < 64){
    s  = ls[t] + ls[t+64] + ls[t+128] + ls[t+192];
    s2 = lq[t] + lq[t+64] + lq[t+128] + lq[t+192];
    atomicAdd(&part[t], s);
    atomicAdd(&part[64+t], s2);
  }
}

__global__ void k_bnfinal(const float* __restrict__ part, const float* __restrict__ gamma,
                          const float* __restrict__ beta, float* __restrict__ bnb, int N){
  int c = threadIdx.x;
  float mu  = part[c] / (float)N;
  float var = part[64+c] / (float)N - mu*mu;
  var = fmaxf(var, 0.f);
  float sc = gamma[c] * rsqrtf(var + 1e-5f);
  bnb[c] = sc;
  bnb[64+c] = beta[c] - mu*sc;
}

// ---- hmid = gelu(bn(g1) + skip + skipb) ----
__global__ void k_fuse1(const float* __restrict__ g1, const float* __restrict__ bn,
                        const float* __restrict__ skip, const float* __restrict__ skipb,
                        float* __restrict__ hmid, int total){
  int i = blockIdx.x*blockDim.x + threadIdx.x;
  if (i < total){
    int c = i & 63;
    float v = fmaf(g1[i], bn[c], bn[64+c]) + skip[i] + skipb[c];
    hmid[i] = gelu_tanh(v);
  }
}

// ---- final: gelu(bn(g2)+hmid), pooled sums per batch (batch_index sorted) ----
__global__ void k_fusepool(const float* __restrict__ g2, const float* __restrict__ bn,
                           const float* __restrict__ hmid, const int* __restrict__ batch,
                           float* __restrict__ pool, float* __restrict__ cnt, int N){
  int t = threadIdx.x; int c = t & 63; int sub = t >> 6;
  int r0 = blockIdx.x*64;
  float scale = bn[c], shift = bn[64+c];
  float acc = 0.f, ca = 0.f; int curb = -1;
  for (int r = r0 + sub; r < N && r < r0 + 64; r += 4){
    int b = batch[r];
    if (b != curb){
      if (curb >= 0){
        atomicAdd(&pool[curb*64 + c], acc);
        if (c == 0) atomicAdd(&cnt[curb], ca);
      }
      acc = 0.f; ca = 0.f; curb = b;
    }
    float v = gelu_tanh(fmaf(g2[(size_t)r*64 + c], scale, shift) + hmid[(size_t)r*64 + c]);
    acc += v; ca += 1.f;
  }
  if (curb >= 0){
    atomicAdd(&pool[curb*64 + c], acc);
    if (c == 0) atomicAdd(&cnt[curb], ca);
  }
}

__global__ void k_out(const float* __restrict__ pool, const float* __restrict__ cnt,
                      float* __restrict__ out, int M){
  int i = blockIdx.x*blockDim.x + threadIdx.x;
  if (i < M) out[i] = pool[i] / fmaxf(cnt[i>>6], 1.f);
}

extern "C" void kernel_launch(void* const* d_in, const int* in_sizes, int n_in,
                              void* d_out, int out_size, void* d_ws, size_t ws_size,
                              hipStream_t stream) {
  const float* x     = (const float*)d_in[0];
  const int*   ei    = (const int*)  d_in[1];
  const int*   batch = (const int*)  d_in[2];
  const float* W1    = (const float*)d_in[3];
  const float* as1   = (const float*)d_in[4];
  const float* ad1   = (const float*)d_in[5];
  const float* b1    = (const float*)d_in[6];
  const float* skW   = (const float*)d_in[7];
  const float* skb   = (const float*)d_in[8];
  const float* gm1   = (const float*)d_in[9];
  const float* bt1   = (const float*)d_in[10];
  const float* W2    = (const float*)d_in[11];
  const float* as2   = (const float*)d_in[12];
  const float* ad2   = (const float*)d_in[13];
  const float* b2    = (const float*)d_in[14];
  const float* gm2   = (const float*)d_in[15];
  const float* bt2   = (const float*)d_in[16];

  int N = in_sizes[2];
  int E = in_sizes[1] / 2;
  const int* esrc = ei;
  const int* edst = ei + E;
  int NB = (N + 127) >> 7;          // 128-node buckets

  char* wp = (char*)d_ws;
  size_t off = 0;
  auto alloc = [&](size_t bytes)->void*{
    off = (off + 255) & ~(size_t)255;
    void* p = wp + off;
    off += bytes;
    return p;
  };
  int*   ptr   = (int*)  alloc((size_t)(N+1)*4);
  int*   srcs  = (int*)  alloc((size_t)E*4);
  unsigned int* recs = (unsigned int*)alloc((size_t)E*4);
  int*   bhist = (int*)  alloc(512*4);
  int*   boff  = (int*)  alloc(520*4);
  int*   bcur  = (int*)  alloc(512*4);
  unsigned short* hpack = (unsigned short*)alloc((size_t)N*128*2);  // bf16 H
  float* a_s  = (float*)alloc((size_t)N*2*4);
  float* a_d  = (float*)alloc((size_t)N*2*4);
  float* gout = (float*)alloc((size_t)N*64*4);   // GAT raw output (both layers)
  float* skv  = (float*)alloc((size_t)N*64*4);   // x @ skipW
  float* hmid = (float*)alloc((size_t)N*64*4);   // layer-1 final output
  float* zz   = (float*)alloc((size_t)(128+128+4096+64)*4); // zero zone
  float* part1 = zz;
  float* part2 = zz + 128;
  float* pool  = zz + 256;
  float* cnt   = zz + 256 + 4096;
  float* bnb1 = (float*)alloc(128*4);
  float* bnb2 = (float*)alloc(128*4);

  hipMemsetAsync(bhist, 0, 512*4, stream);
  hipMemsetAsync(zz, 0, (size_t)(128+128+4096+64)*4, stream);

  int gg = (N + 31) / 32;

  // CSR build (bucket sort)
  p_hist<<<512, 256, 0, stream>>>(edst, bhist, E, NB);
  p_scan<<<1, 512, 0, stream>>>(bhist, boff, bcur, ptr, NB, N, E);
  p_bin<<<(E + BIN_CHUNK - 1)/BIN_CHUNK, 256, 0, stream>>>(esrc, edst, bcur, recs, E, NB);
  p_csr<<<NB, 256, 0, stream>>>(recs, boff, ptr, srcs, N);

  // layer 1 (W1 + skip + att fused)
  k_gemm<3><<<gg, 192, 0, stream>>>(x, W1, skW, as1, ad1, hpack, skv, a_s, a_d, N);
  k_agg<<<(N+3)/4, 256, 0, stream>>>(hpack, a_s, a_d, ptr, srcs, b1, gout, N);
  k_bnstats<<<256, 256, 0, stream>>>(gout, part1, N);
  k_bnfinal<<<1, 64, 0, stream>>>(part1, gm1, bt1, bnb1, N);
  k_fuse1<<<(N*64 + 255)/256, 256, 0, stream>>>(gout, bnb1, skv, skb, hmid, N*64);

  // layer 2
  k_gemm<2><<<gg, 128, 0, stream>>>(hmid, W2, nullptr, as2, ad2, hpack, nullptr, a_s, a_d, N);
  k_agg<<<(N+3)/4, 256, 0, stream>>>(hpack, a_s, a_d, ptr, srcs, b2, gout, N);
  k_bnstats<<<256, 256, 0, stream>>>(gout, part2, N);
  k_bnfinal<<<1, 64, 0, stream>>>(part2, gm2, bt2, bnb2, N);

  // fuse + pool
  k_fusepool<<<(N+63)/64, 256, 0, stream>>>(gout, bnb2, hmid, batch, pool, cnt, N);
  k_out<<<(out_size + 255)/256, 256, 0, stream>>>(pool, cnt, (float*)d_out, out_size);
}